// Round 2
// baseline (588.183 us; speedup 1.0000x reference)
//
#include <hip/hip_runtime.h>
#include <hip/hip_bf16.h>

#define N_NODES 50000
#define N_EDGES 800000
#define N_GRAPHS 64

// ---------------------------------------------------------------- CSR build
__global__ void build_deg_kernel(const int* __restrict__ dst, int* __restrict__ deg, int E) {
    int tid = blockIdx.x * blockDim.x + threadIdx.x;
    if (tid < E) atomicAdd(&deg[dst[tid]], 1);
}

__global__ void scan_kernel(const int* __restrict__ deg, int* __restrict__ row_start,
                            int* __restrict__ cursor, int n) {
    __shared__ int ssum[1024];
    int t = threadIdx.x;
    int chunk = (n + 1023) >> 10;
    int s0 = t * chunk;
    int s1 = min(s0 + chunk, n);
    int local = 0;
    for (int i = s0; i < s1; i++) local += deg[i];
    ssum[t] = local;
    __syncthreads();
    for (int off = 1; off < 1024; off <<= 1) {
        int v = (t >= off) ? ssum[t - off] : 0;
        __syncthreads();
        ssum[t] += v;
        __syncthreads();
    }
    int run = (t == 0) ? 0 : ssum[t - 1];
    for (int i = s0; i < s1; i++) {
        row_start[i] = run;
        cursor[i] = run;
        run += deg[i];
    }
    if (t == 0) row_start[n] = ssum[1023];
}

__global__ void scatter_kernel(const int* __restrict__ src, const int* __restrict__ dst,
                               int* __restrict__ cursor, int* __restrict__ src_sorted, int E) {
    int tid = blockIdx.x * blockDim.x + threadIdx.x;
    if (tid < E) {
        int d = dst[tid];
        int p = atomicAdd(&cursor[d], 1);
        src_sorted[p] = src[tid];
    }
}

// ---------------------------------------------------------------- GEMM: H[M,128] = X[M,128] @ W[128,128], fp32
// BM=64, BN=128, BK=64; 256 threads; each thread 4 rows x 8 cols.
__global__ __launch_bounds__(256) void gemm_xw(const float* __restrict__ X,
                                               const float* __restrict__ W,
                                               float* __restrict__ H, int M) {
    __shared__ float xs[64][68];   // +4 pad: banks (r*4+k)%32 -> conflict-free a-loads
    __shared__ float ws[64][128];
    int t = threadIdx.x;
    int bm = blockIdx.x * 64;
    int tr = (t >> 4) * 4;
    int tc = (t & 15) * 8;
    float acc[4][8] = {};
    for (int k0 = 0; k0 < 128; k0 += 64) {
        // load X tile 64x64 (1024 float4)
        #pragma unroll
        for (int i = 0; i < 4; i++) {
            int idx = t + i * 256;
            int r = idx >> 4;
            int c4 = idx & 15;
            float4 v = make_float4(0.f, 0.f, 0.f, 0.f);
            int gr = bm + r;
            if (gr < M) v = *(const float4*)&X[(size_t)gr * 128 + k0 + c4 * 4];
            *(float4*)&xs[r][c4 * 4] = v;
        }
        // load W tile 64x128 (2048 float4)
        #pragma unroll
        for (int i = 0; i < 8; i++) {
            int idx = t + i * 256;
            int r = idx >> 5;
            int c4 = idx & 31;
            *(float4*)&ws[r][c4 * 4] = *(const float4*)&W[(size_t)(k0 + r) * 128 + c4 * 4];
        }
        __syncthreads();
        #pragma unroll 8
        for (int k = 0; k < 64; k++) {
            float a[4], b[8];
            #pragma unroll
            for (int i = 0; i < 4; i++) a[i] = xs[tr + i][k];
            #pragma unroll
            for (int j = 0; j < 8; j++) b[j] = ws[k][tc + j];
            #pragma unroll
            for (int i = 0; i < 4; i++)
                #pragma unroll
                for (int j = 0; j < 8; j++)
                    acc[i][j] += a[i] * b[j];
        }
        __syncthreads();
    }
    #pragma unroll
    for (int i = 0; i < 4; i++) {
        int gr = bm + tr + i;
        if (gr < M) {
            *(float4*)&H[(size_t)gr * 128 + tc]     = make_float4(acc[i][0], acc[i][1], acc[i][2], acc[i][3]);
            *(float4*)&H[(size_t)gr * 128 + tc + 4] = make_float4(acc[i][4], acc[i][5], acc[i][6], acc[i][7]);
        }
    }
}

// ---------------------------------------------------------------- matvec: out[n] = dot(F[n,:], vec), wave per node
__global__ __launch_bounds__(256) void matvec_kernel(const float* __restrict__ F,
                                                     const float* __restrict__ vec,
                                                     float* __restrict__ out, int M) {
    int wid = (int)((blockIdx.x * blockDim.x + threadIdx.x) >> 6);
    int lane = threadIdx.x & 63;
    if (wid >= M) return;
    const float* row = F + (size_t)wid * 128;
    float v = row[lane] * vec[lane] + row[64 + lane] * vec[64 + lane];
    #pragma unroll
    for (int off = 32; off; off >>= 1) v += __shfl_xor(v, off, 64);
    if (lane == 0) out[wid] = v;
}

// wv[i] = sum_j W[i,j] * att[j]  (128x128 @ 128)
__global__ void wv_kernel(const float* __restrict__ W, const float* __restrict__ att,
                          float* __restrict__ wv) {
    int i = threadIdx.x;
    float s = 0.f;
    for (int j = 0; j < 128; j++) s += W[(size_t)i * 128 + j] * att[j];
    wv[i] = s;
}

// ---------------------------------------------------------------- aggregation: wave per dst node
__global__ __launch_bounds__(256) void aggregate_kernel(
    const float* __restrict__ h, const float* __restrict__ a_src,
    const float* __restrict__ a_dst, const int* __restrict__ row_start,
    const int* __restrict__ src_sorted, const float* __restrict__ bias,
    float* __restrict__ out, int n, int do_relu) {
    int v = blockIdx.x * 4 + (threadIdx.x >> 6);
    if (v >= n) return;
    int lane = threadIdx.x & 63;
    int start = row_start[v];
    int end = row_start[v + 1];
    float adv = a_dst[v];
    const float NEG_INF = -__builtin_inff();

    // pass 1: online softmax stats (m, denom)
    float m = NEG_INF, denom = 0.f;
    for (int c0 = start; c0 < end; c0 += 64) {
        int e = c0 + lane;
        float sc = NEG_INF;
        if (e < end) {
            int s = src_sorted[e];
            sc = a_src[s] + adv;
            sc = sc >= 0.f ? sc : 0.2f * sc;
        }
        float cm = sc;
        #pragma unroll
        for (int off = 32; off; off >>= 1) cm = fmaxf(cm, __shfl_xor(cm, off, 64));
        float nm = fmaxf(m, cm);
        float p = (e < end) ? __expf(sc - nm) : 0.f;
        float cs = p;
        #pragma unroll
        for (int off = 32; off; off >>= 1) cs += __shfl_xor(cs, off, 64);
        denom = denom * __expf(m - nm) + cs;
        m = nm;
    }

    // pass 2: weighted feature accumulation (lane covers features 2*lane, 2*lane+1)
    float acc0 = 0.f, acc1 = 0.f;
    for (int c0 = start; c0 < end; c0 += 64) {
        int e = c0 + lane;
        int s = 0;
        float p = 0.f;
        if (e < end) {
            s = src_sorted[e];
            float sc = a_src[s] + adv;
            sc = sc >= 0.f ? sc : 0.2f * sc;
            p = __expf(sc - m);
        }
        int cnt = min(64, end - c0);
        for (int j = 0; j < cnt; j++) {
            int sj = __shfl(s, j, 64);
            float pj = __shfl(p, j, 64);
            float2 hv = *(const float2*)&h[(size_t)sj * 128 + 2 * lane];
            acc0 += pj * hv.x;
            acc1 += pj * hv.y;
        }
    }
    float inv = 1.f / (denom + 1e-16f);
    float o0 = acc0 * inv + bias[2 * lane];
    float o1 = acc1 * inv + bias[2 * lane + 1];
    if (do_relu) { o0 = fmaxf(o0, 0.f); o1 = fmaxf(o1, 0.f); }
    *(float2*)&out[(size_t)v * 128 + 2 * lane] = make_float2(o0, o1);
}

// ---------------------------------------------------------------- pooling (batch is sorted)
__global__ __launch_bounds__(256) void pool_kernel(const float* __restrict__ feat,
                                                   const int* __restrict__ batch,
                                                   float* __restrict__ sums, int* __restrict__ cnt,
                                                   int n, int chunk) {
    int start = blockIdx.x * chunk;
    int end = min(start + chunk, n);
    int t = threadIdx.x;
    int f = t & 127;
    int po = t >> 7;
    float acc = 0.f;
    int c = 0;
    int cur = -1;
    for (int nn = start + po; nn < end; nn += 2) {
        int g = batch[nn];
        if (g != cur) {
            if (cur >= 0) {
                atomicAdd(&sums[cur * 128 + f], acc);
                if (f == 0) atomicAdd(&cnt[cur], c);
            }
            acc = 0.f; c = 0; cur = g;
        }
        acc += feat[(size_t)nn * 128 + f];
        c++;
    }
    if (cur >= 0) {
        atomicAdd(&sums[cur * 128 + f], acc);
        if (f == 0) atomicAdd(&cnt[cur], c);
    }
}

// out[g,o] = (sums[g,:]/cnt[g]) @ W_lin[:,o] + b_lin[o]
__global__ void final_kernel(const float* __restrict__ sums, const int* __restrict__ cnt,
                             const float* __restrict__ Wl, const float* __restrict__ bl,
                             float* __restrict__ out) {
    int g = blockIdx.x, o = threadIdx.x;
    float invc = 1.f / fmaxf((float)cnt[g], 1.f);
    float acc = bl[o];
    for (int k = 0; k < 128; k++)
        acc += sums[g * 128 + k] * invc * Wl[k * 128 + o];
    out[g * 128 + o] = acc;
}

// ----------------------------------------------------------------
extern "C" void kernel_launch(void* const* d_in, const int* in_sizes, int n_in,
                              void* d_out, int out_size, void* d_ws, size_t ws_size,
                              hipStream_t stream) {
    const float* x        = (const float*)d_in[0];
    const int*   ei       = (const int*)d_in[1];
    const int*   batch    = (const int*)d_in[2];
    const float* W_src1   = (const float*)d_in[3];
    const float* W_dst1   = (const float*)d_in[4];
    const float* att_src1 = (const float*)d_in[5];
    const float* att_dst1 = (const float*)d_in[6];
    const float* bias1    = (const float*)d_in[7];
    const float* W_src2   = (const float*)d_in[8];
    const float* W_dst2   = (const float*)d_in[9];
    const float* att_src2 = (const float*)d_in[10];
    const float* att_dst2 = (const float*)d_in[11];
    const float* bias2    = (const float*)d_in[12];
    const float* W_lin    = (const float*)d_in[13];
    const float* b_lin    = (const float*)d_in[14];
    float* out = (float*)d_out;

    const int N = N_NODES, E = N_EDGES, G = N_GRAPHS;
    const int* src = ei;
    const int* dst = ei + E;

    char* w = (char*)d_ws;
    auto alloc = [&](size_t bytes) -> char* {
        char* p = w;
        w += (bytes + 255) & ~(size_t)255;
        return p;
    };
    int*   deg        = (int*)alloc((size_t)N * 4);
    int*   row_start  = (int*)alloc((size_t)(N + 1) * 4);
    int*   cursor     = (int*)alloc((size_t)N * 4);
    int*   src_sorted = (int*)alloc((size_t)E * 4);
    float* h          = (float*)alloc((size_t)N * 128 * 4);
    float* feat       = (float*)alloc((size_t)N * 128 * 4);
    float* a_src      = (float*)alloc((size_t)N * 4);
    float* a_dst      = (float*)alloc((size_t)N * 4);
    float* wv         = (float*)alloc(128 * 4);
    float* sums       = (float*)alloc((size_t)G * 128 * 4);
    int*   cnt        = (int*)alloc((size_t)G * 4);

    hipMemsetAsync(deg, 0, (size_t)N * 4, stream);
    hipMemsetAsync(sums, 0, (size_t)G * 128 * 4, stream);
    hipMemsetAsync(cnt, 0, (size_t)G * 4, stream);

    build_deg_kernel<<<(E + 255) / 256, 256, 0, stream>>>(dst, deg, E);
    scan_kernel<<<1, 1024, 0, stream>>>(deg, row_start, cursor, N);
    scatter_kernel<<<(E + 255) / 256, 256, 0, stream>>>(src, dst, cursor, src_sorted, E);

    int gemm_grid = (N + 63) / 64;
    int mv_grid = (N * 64 + 255) / 256;
    int agg_grid = (N + 3) / 4;

    // ---- layer 1
    wv_kernel<<<1, 128, 0, stream>>>(W_dst1, att_dst1, wv);
    gemm_xw<<<gemm_grid, 256, 0, stream>>>(x, W_src1, h, N);
    matvec_kernel<<<mv_grid, 256, 0, stream>>>(h, att_src1, a_src, N);
    matvec_kernel<<<mv_grid, 256, 0, stream>>>(x, wv, a_dst, N);
    aggregate_kernel<<<agg_grid, 256, 0, stream>>>(h, a_src, a_dst, row_start, src_sorted,
                                                   bias1, feat, N, 1);
    // ---- layer 2
    wv_kernel<<<1, 128, 0, stream>>>(W_dst2, att_dst2, wv);
    gemm_xw<<<gemm_grid, 256, 0, stream>>>(feat, W_src2, h, N);
    matvec_kernel<<<mv_grid, 256, 0, stream>>>(h, att_src2, a_src, N);
    matvec_kernel<<<mv_grid, 256, 0, stream>>>(feat, wv, a_dst, N);
    aggregate_kernel<<<agg_grid, 256, 0, stream>>>(h, a_src, a_dst, row_start, src_sorted,
                                                   bias2, feat, N, 1);
    // ---- pool + linear
    int chunk = (N + 255) / 256;
    pool_kernel<<<256, 256, 0, stream>>>(feat, batch, sums, cnt, N, chunk);
    final_kernel<<<G, 128, 0, stream>>>(sums, cnt, W_lin, b_lin, out);
}

// Round 3
// 429.646 us; speedup vs baseline: 1.3690x; 1.3690x over previous
//
#include <hip/hip_runtime.h>
#include <hip/hip_bf16.h>
#include <hip/hip_fp16.h>

#define N_NODES 50000
#define N_EDGES 800000
#define N_GRAPHS 64

// ---------------------------------------------------------------- CSR build
__global__ void build_deg_kernel(const int* __restrict__ dst, int* __restrict__ deg, int E) {
    int tid = blockIdx.x * blockDim.x + threadIdx.x;
    if (tid < E) atomicAdd(&deg[dst[tid]], 1);
}

// ---- multi-block scan: 1024 elements per block
__global__ __launch_bounds__(256) void scan_partial(const int* __restrict__ deg,
                                                    int* __restrict__ block_sums, int n) {
    int b = blockIdx.x, t = threadIdx.x;
    int base = b * 1024 + t * 4;
    int4 v = make_int4(0, 0, 0, 0);
    if (base + 3 < n) v = *(const int4*)&deg[base];
    else {
        if (base + 0 < n) v.x = deg[base + 0];
        if (base + 1 < n) v.y = deg[base + 1];
        if (base + 2 < n) v.z = deg[base + 2];
    }
    int s = v.x + v.y + v.z + v.w;
    __shared__ int sm[256];
    sm[t] = s;
    __syncthreads();
    for (int off = 128; off; off >>= 1) {
        if (t < off) sm[t] += sm[t + off];
        __syncthreads();
    }
    if (t == 0) block_sums[b] = sm[0];
}

__global__ void scan_offsets(const int* __restrict__ block_sums, int* __restrict__ block_off,
                             int nb, int* __restrict__ total_out) {
    int lane = threadIdx.x;  // 64 threads
    int bs = (lane < nb) ? block_sums[lane] : 0;
    int v = bs;
    #pragma unroll
    for (int off = 1; off < 64; off <<= 1) {
        int u = __shfl_up(v, off, 64);
        if (lane >= off) v += u;
    }
    if (lane < nb) block_off[lane] = v - bs;   // exclusive
    if (lane == 63) *total_out = v;            // grand total -> row_start[n]
}

__global__ __launch_bounds__(256) void scan_final(const int* __restrict__ deg,
                                                  const int* __restrict__ block_off,
                                                  int* __restrict__ row_start,
                                                  int* __restrict__ cursor, int n) {
    int b = blockIdx.x, t = threadIdx.x;
    int base = b * 1024 + t * 4;
    int4 v = make_int4(0, 0, 0, 0);
    if (base + 3 < n) v = *(const int4*)&deg[base];
    else {
        if (base + 0 < n) v.x = deg[base + 0];
        if (base + 1 < n) v.y = deg[base + 1];
        if (base + 2 < n) v.z = deg[base + 2];
    }
    int s = v.x + v.y + v.z + v.w;
    __shared__ int sm[256];
    sm[t] = s;
    __syncthreads();
    for (int off = 1; off < 256; off <<= 1) {
        int u = (t >= off) ? sm[t - off] : 0;
        __syncthreads();
        sm[t] += u;
        __syncthreads();
    }
    int ex = block_off[b] + ((t == 0) ? 0 : sm[t - 1]);
    int r0 = ex, r1 = r0 + v.x, r2 = r1 + v.y, r3 = r2 + v.z;
    if (base + 0 < n) { row_start[base + 0] = r0; cursor[base + 0] = r0; }
    if (base + 1 < n) { row_start[base + 1] = r1; cursor[base + 1] = r1; }
    if (base + 2 < n) { row_start[base + 2] = r2; cursor[base + 2] = r2; }
    if (base + 3 < n) { row_start[base + 3] = r3; cursor[base + 3] = r3; }
}

__global__ void scatter_kernel(const int* __restrict__ src, const int* __restrict__ dst,
                               int* __restrict__ cursor, int* __restrict__ src_sorted, int E) {
    int tid = blockIdx.x * blockDim.x + threadIdx.x;
    if (tid < E) {
        int d = dst[tid];
        int p = atomicAdd(&cursor[d], 1);
        src_sorted[p] = src[tid];
    }
}

// ---------------------------------------------------------------- GEMM: Hh[M,128](fp16) = X[M,128] @ W[128,128]
// fused: a_out[r] = (X@W)[r,:] . att
__global__ __launch_bounds__(256) void gemm_xw_fused(const float* __restrict__ X,
                                                     const float* __restrict__ W,
                                                     const float* __restrict__ att,
                                                     __half* __restrict__ Hh,
                                                     float* __restrict__ a_out, int M) {
    __shared__ float xs[64][68];
    __shared__ float ws[64][128];
    int t = threadIdx.x;
    int bm = blockIdx.x * 64;
    int tr = (t >> 4) * 4;
    int tc = (t & 15) * 8;
    float acc[4][8] = {};
    float att_r[8];
    #pragma unroll
    for (int j = 0; j < 8; j++) att_r[j] = att[tc + j];
    for (int k0 = 0; k0 < 128; k0 += 64) {
        #pragma unroll
        for (int i = 0; i < 4; i++) {
            int idx = t + i * 256;
            int r = idx >> 4;
            int c4 = idx & 15;
            float4 v = make_float4(0.f, 0.f, 0.f, 0.f);
            int gr = bm + r;
            if (gr < M) v = *(const float4*)&X[(size_t)gr * 128 + k0 + c4 * 4];
            *(float4*)&xs[r][c4 * 4] = v;
        }
        #pragma unroll
        for (int i = 0; i < 8; i++) {
            int idx = t + i * 256;
            int r = idx >> 5;
            int c4 = idx & 31;
            *(float4*)&ws[r][c4 * 4] = *(const float4*)&W[(size_t)(k0 + r) * 128 + c4 * 4];
        }
        __syncthreads();
        #pragma unroll 8
        for (int k = 0; k < 64; k++) {
            float a[4], b[8];
            #pragma unroll
            for (int i = 0; i < 4; i++) a[i] = xs[tr + i][k];
            #pragma unroll
            for (int j = 0; j < 8; j++) b[j] = ws[k][tc + j];
            #pragma unroll
            for (int i = 0; i < 4; i++)
                #pragma unroll
                for (int j = 0; j < 8; j++)
                    acc[i][j] += a[i] * b[j];
        }
        __syncthreads();
    }
    // epilogue: fp16 store + fused a_src
    float pr[4];
    #pragma unroll
    for (int i = 0; i < 4; i++) {
        pr[i] = 0.f;
        #pragma unroll
        for (int j = 0; j < 8; j++) pr[i] += acc[i][j] * att_r[j];
    }
    #pragma unroll
    for (int off = 1; off < 16; off <<= 1) {
        #pragma unroll
        for (int i = 0; i < 4; i++) pr[i] += __shfl_xor(pr[i], off, 64);
    }
    #pragma unroll
    for (int i = 0; i < 4; i++) {
        int gr = bm + tr + i;
        if (gr < M) {
            __half hrow[8];
            #pragma unroll
            for (int j = 0; j < 8; j++) hrow[j] = __float2half(acc[i][j]);
            *(float4*)&Hh[(size_t)gr * 128 + tc] = *(const float4*)hrow;
            if ((t & 15) == 0) a_out[gr] = pr[i];
        }
    }
}

// ---------------------------------------------------------------- matvec: out[n] = dot(F[n,:], vec) (fp32)
__global__ __launch_bounds__(256) void matvec_kernel(const float* __restrict__ F,
                                                     const float* __restrict__ vec,
                                                     float* __restrict__ out, int M) {
    int wid = (int)((blockIdx.x * blockDim.x + threadIdx.x) >> 6);
    int lane = threadIdx.x & 63;
    if (wid >= M) return;
    const float* row = F + (size_t)wid * 128;
    float v = row[lane] * vec[lane] + row[64 + lane] * vec[64 + lane];
    #pragma unroll
    for (int off = 32; off; off >>= 1) v += __shfl_xor(v, off, 64);
    if (lane == 0) out[wid] = v;
}

// wv[i] = sum_j W[i,j] * att[j]
__global__ void wv_kernel(const float* __restrict__ W, const float* __restrict__ att,
                          float* __restrict__ wv) {
    int i = threadIdx.x;
    float s = 0.f;
    for (int j = 0; j < 128; j++) s += W[(size_t)i * 128 + j] * att[j];
    wv[i] = s;
}

// ---------------------------------------------------------------- aggregation: wave per dst node, single pass
__global__ __launch_bounds__(256) void aggregate_kernel(
    const __half2* __restrict__ h2, const float* __restrict__ a_src,
    const float* __restrict__ a_dst, const int* __restrict__ row_start,
    const int* __restrict__ src_sorted, const float* __restrict__ bias,
    float* __restrict__ out, int n, int do_relu) {
    int v = blockIdx.x * 4 + (threadIdx.x >> 6);
    if (v >= n) return;
    int lane = threadIdx.x & 63;
    int start = row_start[v];
    int end = row_start[v + 1];
    float adv = a_dst[v];
    const __half2* hbase = h2 + lane;

    float denom = 0.f, acc0 = 0.f, acc1 = 0.f;
    for (int c0 = start; c0 < end; c0 += 64) {
        int e = c0 + lane;
        int s = 0;
        float p = 0.f;
        if (e < end) {
            s = src_sorted[e];
            float sc = a_src[s] + adv;
            sc = sc >= 0.f ? sc : 0.2f * sc;
            p = __expf(sc);   // no max-subtraction: scores are O(10), safe in fp32
        }
        int cnt = min(64, end - c0);
        for (int j = 0; j < cnt; j++) {
            int sj = __shfl(s, j, 64);
            float pj = __shfl(p, j, 64);
            float2 f = __half22float2(hbase[(size_t)sj * 64]);
            denom += pj;
            acc0 += pj * f.x;
            acc1 += pj * f.y;
        }
    }
    float inv = 1.f / (denom + 1e-16f);
    float o0 = acc0 * inv + bias[2 * lane];
    float o1 = acc1 * inv + bias[2 * lane + 1];
    if (do_relu) { o0 = fmaxf(o0, 0.f); o1 = fmaxf(o1, 0.f); }
    *(float2*)&out[(size_t)v * 128 + 2 * lane] = make_float2(o0, o1);
}

// ---------------------------------------------------------------- pooling (batch is sorted)
__global__ __launch_bounds__(256) void pool_kernel(const float* __restrict__ feat,
                                                   const int* __restrict__ batch,
                                                   float* __restrict__ sums, int* __restrict__ cnt,
                                                   int n, int chunk) {
    int start = blockIdx.x * chunk;
    int end = min(start + chunk, n);
    int t = threadIdx.x;
    int f = t & 127;
    int po = t >> 7;
    float acc = 0.f;
    int c = 0;
    int cur = -1;
    for (int nn = start + po; nn < end; nn += 2) {
        int g = batch[nn];
        if (g != cur) {
            if (cur >= 0) {
                atomicAdd(&sums[cur * 128 + f], acc);
                if (f == 0) atomicAdd(&cnt[cur], c);
            }
            acc = 0.f; c = 0; cur = g;
        }
        acc += feat[(size_t)nn * 128 + f];
        c++;
    }
    if (cur >= 0) {
        atomicAdd(&sums[cur * 128 + f], acc);
        if (f == 0) atomicAdd(&cnt[cur], c);
    }
}

__global__ void final_kernel(const float* __restrict__ sums, const int* __restrict__ cnt,
                             const float* __restrict__ Wl, const float* __restrict__ bl,
                             float* __restrict__ out) {
    int g = blockIdx.x, o = threadIdx.x;
    float invc = 1.f / fmaxf((float)cnt[g], 1.f);
    float acc = bl[o];
    for (int k = 0; k < 128; k++)
        acc += sums[g * 128 + k] * invc * Wl[k * 128 + o];
    out[g * 128 + o] = acc;
}

// ----------------------------------------------------------------
extern "C" void kernel_launch(void* const* d_in, const int* in_sizes, int n_in,
                              void* d_out, int out_size, void* d_ws, size_t ws_size,
                              hipStream_t stream) {
    const float* x        = (const float*)d_in[0];
    const int*   ei       = (const int*)d_in[1];
    const int*   batch    = (const int*)d_in[2];
    const float* W_src1   = (const float*)d_in[3];
    const float* W_dst1   = (const float*)d_in[4];
    const float* att_src1 = (const float*)d_in[5];
    const float* att_dst1 = (const float*)d_in[6];
    const float* bias1    = (const float*)d_in[7];
    const float* W_src2   = (const float*)d_in[8];
    const float* W_dst2   = (const float*)d_in[9];
    const float* att_src2 = (const float*)d_in[10];
    const float* att_dst2 = (const float*)d_in[11];
    const float* bias2    = (const float*)d_in[12];
    const float* W_lin    = (const float*)d_in[13];
    const float* b_lin    = (const float*)d_in[14];
    float* out = (float*)d_out;

    const int N = N_NODES, E = N_EDGES, G = N_GRAPHS;
    const int NB = (N + 1023) / 1024;   // scan blocks
    const int* src = ei;
    const int* dst = ei + E;

    char* w = (char*)d_ws;
    auto alloc = [&](size_t bytes) -> char* {
        char* p = w;
        w += (bytes + 255) & ~(size_t)255;
        return p;
    };
    // deg/sums/cnt contiguous -> single memset
    int*   deg        = (int*)alloc((size_t)N * 4);          // 200000 B (pad to 200192)
    float* sums       = (float*)alloc((size_t)G * 128 * 4);  // 32768 B
    int*   cnt        = (int*)alloc((size_t)G * 4);          // 256 B
    size_t zero_bytes = ((size_t)N * 4 + 255 & ~(size_t)255) + ((size_t)G * 128 * 4 + 255 & ~(size_t)255) + 256;

    int*   row_start  = (int*)alloc((size_t)(N + 1) * 4);
    int*   cursor     = (int*)alloc((size_t)N * 4);
    int*   block_sums = (int*)alloc(64 * 4);
    int*   block_off  = (int*)alloc(64 * 4);
    int*   src_sorted = (int*)alloc((size_t)E * 4);
    __half* h_half    = (__half*)alloc((size_t)N * 128 * 2);
    float* feat       = (float*)alloc((size_t)N * 128 * 4);
    float* a_src      = (float*)alloc((size_t)N * 4);
    float* a_dst      = (float*)alloc((size_t)N * 4);
    float* wv         = (float*)alloc(128 * 4);

    hipMemsetAsync(deg, 0, zero_bytes, stream);

    build_deg_kernel<<<(E + 255) / 256, 256, 0, stream>>>(dst, deg, E);
    scan_partial<<<NB, 256, 0, stream>>>(deg, block_sums, N);
    scan_offsets<<<1, 64, 0, stream>>>(block_sums, block_off, NB, &row_start[N]);
    scan_final<<<NB, 256, 0, stream>>>(deg, block_off, row_start, cursor, N);
    scatter_kernel<<<(E + 255) / 256, 256, 0, stream>>>(src, dst, cursor, src_sorted, E);

    int gemm_grid = (N + 63) / 64;
    int mv_grid = (N * 64 + 255) / 256;
    int agg_grid = (N + 3) / 4;

    // ---- layer 1
    wv_kernel<<<1, 128, 0, stream>>>(W_dst1, att_dst1, wv);
    gemm_xw_fused<<<gemm_grid, 256, 0, stream>>>(x, W_src1, att_src1, h_half, a_src, N);
    matvec_kernel<<<mv_grid, 256, 0, stream>>>(x, wv, a_dst, N);
    aggregate_kernel<<<agg_grid, 256, 0, stream>>>((const __half2*)h_half, a_src, a_dst,
                                                   row_start, src_sorted, bias1, feat, N, 1);
    // ---- layer 2
    wv_kernel<<<1, 128, 0, stream>>>(W_dst2, att_dst2, wv);
    gemm_xw_fused<<<gemm_grid, 256, 0, stream>>>(feat, W_src2, att_src2, h_half, a_src, N);
    matvec_kernel<<<mv_grid, 256, 0, stream>>>(feat, wv, a_dst, N);
    aggregate_kernel<<<agg_grid, 256, 0, stream>>>((const __half2*)h_half, a_src, a_dst,
                                                   row_start, src_sorted, bias2, feat, N, 1);
    // ---- pool + linear
    int chunk = (N + 255) / 256;
    pool_kernel<<<256, 256, 0, stream>>>(feat, batch, sums, cnt, N, chunk);
    final_kernel<<<G, 128, 0, stream>>>(sums, cnt, W_lin, b_lin, out);
}

// Round 4
// 367.967 us; speedup vs baseline: 1.5985x; 1.1676x over previous
//
#include <hip/hip_runtime.h>
#include <hip/hip_bf16.h>
#include <hip/hip_fp16.h>

#define N_NODES 50000
#define N_EDGES 800000
#define N_GRAPHS 64

// ---------------------------------------------------------------- CSR build
__global__ void build_deg_kernel(const int* __restrict__ dst, int* __restrict__ deg, int E) {
    int tid = blockIdx.x * blockDim.x + threadIdx.x;
    if (tid < E) atomicAdd(&deg[dst[tid]], 1);
}

// ---- multi-block scan: 1024 elements per block
__global__ __launch_bounds__(256) void scan_partial(const int* __restrict__ deg,
                                                    int* __restrict__ block_sums, int n) {
    int b = blockIdx.x, t = threadIdx.x;
    int base = b * 1024 + t * 4;
    int4 v = make_int4(0, 0, 0, 0);
    if (base + 3 < n) v = *(const int4*)&deg[base];
    else {
        if (base + 0 < n) v.x = deg[base + 0];
        if (base + 1 < n) v.y = deg[base + 1];
        if (base + 2 < n) v.z = deg[base + 2];
    }
    int s = v.x + v.y + v.z + v.w;
    __shared__ int sm[256];
    sm[t] = s;
    __syncthreads();
    for (int off = 128; off; off >>= 1) {
        if (t < off) sm[t] += sm[t + off];
        __syncthreads();
    }
    if (t == 0) block_sums[b] = sm[0];
}

__global__ void scan_offsets(const int* __restrict__ block_sums, int* __restrict__ block_off,
                             int nb, int* __restrict__ total_out) {
    int lane = threadIdx.x;  // 64 threads
    int bs = (lane < nb) ? block_sums[lane] : 0;
    int v = bs;
    #pragma unroll
    for (int off = 1; off < 64; off <<= 1) {
        int u = __shfl_up(v, off, 64);
        if (lane >= off) v += u;
    }
    if (lane < nb) block_off[lane] = v - bs;   // exclusive
    if (lane == 63) *total_out = v;            // grand total -> row_start[n]
}

__global__ __launch_bounds__(256) void scan_final(const int* __restrict__ deg,
                                                  const int* __restrict__ block_off,
                                                  int* __restrict__ row_start,
                                                  int* __restrict__ cursor, int n) {
    int b = blockIdx.x, t = threadIdx.x;
    int base = b * 1024 + t * 4;
    int4 v = make_int4(0, 0, 0, 0);
    if (base + 3 < n) v = *(const int4*)&deg[base];
    else {
        if (base + 0 < n) v.x = deg[base + 0];
        if (base + 1 < n) v.y = deg[base + 1];
        if (base + 2 < n) v.z = deg[base + 2];
    }
    int s = v.x + v.y + v.z + v.w;
    __shared__ int sm[256];
    sm[t] = s;
    __syncthreads();
    for (int off = 1; off < 256; off <<= 1) {
        int u = (t >= off) ? sm[t - off] : 0;
        __syncthreads();
        sm[t] += u;
        __syncthreads();
    }
    int ex = block_off[b] + ((t == 0) ? 0 : sm[t - 1]);
    int r0 = ex, r1 = r0 + v.x, r2 = r1 + v.y, r3 = r2 + v.z;
    if (base + 0 < n) { row_start[base + 0] = r0; cursor[base + 0] = r0; }
    if (base + 1 < n) { row_start[base + 1] = r1; cursor[base + 1] = r1; }
    if (base + 2 < n) { row_start[base + 2] = r2; cursor[base + 2] = r2; }
    if (base + 3 < n) { row_start[base + 3] = r3; cursor[base + 3] = r3; }
}

__global__ void scatter_kernel(const int* __restrict__ src, const int* __restrict__ dst,
                               int* __restrict__ cursor, int* __restrict__ src_sorted, int E) {
    int tid = blockIdx.x * blockDim.x + threadIdx.x;
    if (tid < E) {
        int d = dst[tid];
        int p = atomicAdd(&cursor[d], 1);
        src_sorted[p] = src[tid];
    }
}

// both layers' wv in one launch: wv[i] = sum_j W[i,j]*att[j]
__global__ void wv_both_kernel(const float* __restrict__ W1, const float* __restrict__ a1,
                               const float* __restrict__ W2, const float* __restrict__ a2,
                               float* __restrict__ wv) {
    int t = threadIdx.x;                 // 256
    const float* W = (t < 128) ? W1 : W2;
    const float* a = (t < 128) ? a1 : a2;
    int i = t & 127;
    float s = 0.f;
    for (int j = 0; j < 128; j++) s += W[(size_t)i * 128 + j] * a[j];
    wv[t] = s;   // wv[0:128] = layer1, wv[128:256] = layer2
}

// ---------------------------------------------------------------- GEMM: Hh[M,128](fp16) = X[M,128] @ W[128,128]
// fused: a_src_out[r] = (X@W)[r,:] . att ;  a_dst_out[r] = X[r,:] . wv
__global__ __launch_bounds__(256) void gemm_xw_fused(const float* __restrict__ X,
                                                     const float* __restrict__ W,
                                                     const float* __restrict__ att,
                                                     const float* __restrict__ wv,
                                                     __half* __restrict__ Hh,
                                                     float* __restrict__ a_src_out,
                                                     float* __restrict__ a_dst_out, int M) {
    __shared__ float xs[64][68];
    __shared__ float ws[64][128];
    int t = threadIdx.x;
    int bm = blockIdx.x * 64;
    int tr = (t >> 4) * 4;
    int tc = (t & 15) * 8;
    int q = t & 15;
    float acc[4][8] = {};
    float adp[4] = {};
    float att_r[8];
    #pragma unroll
    for (int j = 0; j < 8; j++) att_r[j] = att[tc + j];
    for (int k0 = 0; k0 < 128; k0 += 64) {
        #pragma unroll
        for (int i = 0; i < 4; i++) {
            int idx = t + i * 256;
            int r = idx >> 4;
            int c4 = idx & 15;
            float4 v = make_float4(0.f, 0.f, 0.f, 0.f);
            int gr = bm + r;
            if (gr < M) v = *(const float4*)&X[(size_t)gr * 128 + k0 + c4 * 4];
            *(float4*)&xs[r][c4 * 4] = v;
        }
        #pragma unroll
        for (int i = 0; i < 8; i++) {
            int idx = t + i * 256;
            int r = idx >> 5;
            int c4 = idx & 31;
            *(float4*)&ws[r][c4 * 4] = *(const float4*)&W[(size_t)(k0 + r) * 128 + c4 * 4];
        }
        __syncthreads();
        #pragma unroll 8
        for (int k = 0; k < 64; k++) {
            float a[4], b[8];
            #pragma unroll
            for (int i = 0; i < 4; i++) a[i] = xs[tr + i][k];
            #pragma unroll
            for (int j = 0; j < 8; j++) b[j] = ws[k][tc + j];
            #pragma unroll
            for (int i = 0; i < 4; i++)
                #pragma unroll
                for (int j = 0; j < 8; j++)
                    acc[i][j] += a[i] * b[j];
        }
        // fused partial dot for a_dst: this thread covers k-slice [q*4, q*4+4)
        #pragma unroll
        for (int kk = 0; kk < 4; kk++) {
            float wvk = wv[k0 + q * 4 + kk];
            #pragma unroll
            for (int i = 0; i < 4; i++) adp[i] += xs[tr + i][q * 4 + kk] * wvk;
        }
        __syncthreads();
    }
    // epilogue: fp16 store + fused a_src/a_dst
    float pr[4];
    #pragma unroll
    for (int i = 0; i < 4; i++) {
        pr[i] = 0.f;
        #pragma unroll
        for (int j = 0; j < 8; j++) pr[i] += acc[i][j] * att_r[j];
    }
    #pragma unroll
    for (int off = 1; off < 16; off <<= 1) {
        #pragma unroll
        for (int i = 0; i < 4; i++) {
            pr[i] += __shfl_xor(pr[i], off, 64);
            adp[i] += __shfl_xor(adp[i], off, 64);
        }
    }
    #pragma unroll
    for (int i = 0; i < 4; i++) {
        int gr = bm + tr + i;
        if (gr < M) {
            __half hrow[8];
            #pragma unroll
            for (int j = 0; j < 8; j++) hrow[j] = __float2half(acc[i][j]);
            *(float4*)&Hh[(size_t)gr * 128 + tc] = *(const float4*)hrow;
            if (q == 0) { a_src_out[gr] = pr[i]; a_dst_out[gr] = adp[i]; }
        }
    }
}

// ---------------------------------------------------------------- aggregation: wave per dst node, single pass, 8x ILP
__global__ __launch_bounds__(256) void aggregate_kernel(
    const __half2* __restrict__ h2, const float* __restrict__ a_src,
    const float* __restrict__ a_dst, const int* __restrict__ row_start,
    const int* __restrict__ src_sorted, const float* __restrict__ bias,
    float* __restrict__ out, int n, int do_relu) {
    int v = blockIdx.x * 4 + (threadIdx.x >> 6);
    if (v >= n) return;
    int lane = threadIdx.x & 63;
    int start = row_start[v];
    int end = row_start[v + 1];
    float adv = a_dst[v];
    const __half2* hbase = h2 + lane;

    float denom = 0.f, acc0 = 0.f, acc1 = 0.f;
    for (int c0 = start; c0 < end; c0 += 64) {
        int e = c0 + lane;
        int s = 0;
        float p = 0.f;
        if (e < end) {
            int si = src_sorted[e];
            s = si;
            float sc = a_src[si] + adv;
            sc = sc >= 0.f ? sc : 0.2f * sc;
            p = __expf(sc);   // scores are O(10): no max-subtraction needed in fp32
        }
        int cnt = min(64, end - c0);
        int j = 0;
        for (; j + 8 <= cnt; j += 8) {
            int   s0 = __shfl(s, j + 0, 64), s1 = __shfl(s, j + 1, 64),
                  s2 = __shfl(s, j + 2, 64), s3 = __shfl(s, j + 3, 64),
                  s4 = __shfl(s, j + 4, 64), s5 = __shfl(s, j + 5, 64),
                  s6 = __shfl(s, j + 6, 64), s7 = __shfl(s, j + 7, 64);
            float p0 = __shfl(p, j + 0, 64), p1 = __shfl(p, j + 1, 64),
                  p2 = __shfl(p, j + 2, 64), p3 = __shfl(p, j + 3, 64),
                  p4 = __shfl(p, j + 4, 64), p5 = __shfl(p, j + 5, 64),
                  p6 = __shfl(p, j + 6, 64), p7 = __shfl(p, j + 7, 64);
            __half2 r0 = hbase[(size_t)s0 * 64], r1 = hbase[(size_t)s1 * 64],
                    r2 = hbase[(size_t)s2 * 64], r3 = hbase[(size_t)s3 * 64],
                    r4 = hbase[(size_t)s4 * 64], r5 = hbase[(size_t)s5 * 64],
                    r6 = hbase[(size_t)s6 * 64], r7 = hbase[(size_t)s7 * 64];
            denom += (p0 + p1 + p2 + p3) + (p4 + p5 + p6 + p7);
            float2 f;
            f = __half22float2(r0); acc0 += p0 * f.x; acc1 += p0 * f.y;
            f = __half22float2(r1); acc0 += p1 * f.x; acc1 += p1 * f.y;
            f = __half22float2(r2); acc0 += p2 * f.x; acc1 += p2 * f.y;
            f = __half22float2(r3); acc0 += p3 * f.x; acc1 += p3 * f.y;
            f = __half22float2(r4); acc0 += p4 * f.x; acc1 += p4 * f.y;
            f = __half22float2(r5); acc0 += p5 * f.x; acc1 += p5 * f.y;
            f = __half22float2(r6); acc0 += p6 * f.x; acc1 += p6 * f.y;
            f = __half22float2(r7); acc0 += p7 * f.x; acc1 += p7 * f.y;
        }
        for (; j < cnt; j++) {
            int sj = __shfl(s, j, 64);
            float pj = __shfl(p, j, 64);
            float2 f = __half22float2(hbase[(size_t)sj * 64]);
            denom += pj;
            acc0 += pj * f.x;
            acc1 += pj * f.y;
        }
    }
    float inv = 1.f / (denom + 1e-16f);
    float o0 = acc0 * inv + bias[2 * lane];
    float o1 = acc1 * inv + bias[2 * lane + 1];
    if (do_relu) { o0 = fmaxf(o0, 0.f); o1 = fmaxf(o1, 0.f); }
    *(float2*)&out[(size_t)v * 128 + 2 * lane] = make_float2(o0, o1);
}

// ---------------------------------------------------------------- pooling (batch is sorted)
__global__ __launch_bounds__(256) void pool_kernel(const float* __restrict__ feat,
                                                   const int* __restrict__ batch,
                                                   float* __restrict__ sums, int* __restrict__ cnt,
                                                   int n, int chunk) {
    int start = blockIdx.x * chunk;
    int end = min(start + chunk, n);
    int t = threadIdx.x;
    int f = t & 127;
    int po = t >> 7;
    float acc = 0.f;
    int c = 0;
    int cur = -1;
    for (int nn = start + po; nn < end; nn += 2) {
        int g = batch[nn];
        if (g != cur) {
            if (cur >= 0) {
                atomicAdd(&sums[cur * 128 + f], acc);
                if (f == 0) atomicAdd(&cnt[cur], c);
            }
            acc = 0.f; c = 0; cur = g;
        }
        acc += feat[(size_t)nn * 128 + f];
        c++;
    }
    if (cur >= 0) {
        atomicAdd(&sums[cur * 128 + f], acc);
        if (f == 0) atomicAdd(&cnt[cur], c);
    }
}

__global__ void final_kernel(const float* __restrict__ sums, const int* __restrict__ cnt,
                             const float* __restrict__ Wl, const float* __restrict__ bl,
                             float* __restrict__ out) {
    int g = blockIdx.x, o = threadIdx.x;
    float invc = 1.f / fmaxf((float)cnt[g], 1.f);
    float acc = bl[o];
    for (int k = 0; k < 128; k++)
        acc += sums[g * 128 + k] * invc * Wl[k * 128 + o];
    out[g * 128 + o] = acc;
}

// ----------------------------------------------------------------
extern "C" void kernel_launch(void* const* d_in, const int* in_sizes, int n_in,
                              void* d_out, int out_size, void* d_ws, size_t ws_size,
                              hipStream_t stream) {
    const float* x        = (const float*)d_in[0];
    const int*   ei       = (const int*)d_in[1];
    const int*   batch    = (const int*)d_in[2];
    const float* W_src1   = (const float*)d_in[3];
    const float* W_dst1   = (const float*)d_in[4];
    const float* att_src1 = (const float*)d_in[5];
    const float* att_dst1 = (const float*)d_in[6];
    const float* bias1    = (const float*)d_in[7];
    const float* W_src2   = (const float*)d_in[8];
    const float* W_dst2   = (const float*)d_in[9];
    const float* att_src2 = (const float*)d_in[10];
    const float* att_dst2 = (const float*)d_in[11];
    const float* bias2    = (const float*)d_in[12];
    const float* W_lin    = (const float*)d_in[13];
    const float* b_lin    = (const float*)d_in[14];
    float* out = (float*)d_out;

    const int N = N_NODES, E = N_EDGES, G = N_GRAPHS;
    const int NB = (N + 1023) / 1024;
    const int* src = ei;
    const int* dst = ei + E;

    char* w = (char*)d_ws;
    auto alloc = [&](size_t bytes) -> char* {
        char* p = w;
        w += (bytes + 255) & ~(size_t)255;
        return p;
    };
    // deg/sums/cnt contiguous -> single memset
    int*   deg        = (int*)alloc((size_t)N * 4);
    float* sums       = (float*)alloc((size_t)G * 128 * 4);
    int*   cnt        = (int*)alloc((size_t)G * 4);
    size_t zero_bytes = (((size_t)N * 4 + 255) & ~(size_t)255) + (((size_t)G * 128 * 4 + 255) & ~(size_t)255) + 256;

    int*   row_start  = (int*)alloc((size_t)(N + 1) * 4);
    int*   cursor     = (int*)alloc((size_t)N * 4);
    int*   block_sums = (int*)alloc(64 * 4);
    int*   block_off  = (int*)alloc(64 * 4);
    int*   src_sorted = (int*)alloc((size_t)E * 4);
    __half* h_half    = (__half*)alloc((size_t)N * 128 * 2);
    float* feat       = (float*)alloc((size_t)N * 128 * 4);
    float* a_src      = (float*)alloc((size_t)N * 4);
    float* a_dst      = (float*)alloc((size_t)N * 4);
    float* wv         = (float*)alloc(256 * 4);

    hipMemsetAsync(deg, 0, zero_bytes, stream);

    build_deg_kernel<<<(E + 255) / 256, 256, 0, stream>>>(dst, deg, E);
    scan_partial<<<NB, 256, 0, stream>>>(deg, block_sums, N);
    scan_offsets<<<1, 64, 0, stream>>>(block_sums, block_off, NB, &row_start[N]);
    scan_final<<<NB, 256, 0, stream>>>(deg, block_off, row_start, cursor, N);
    scatter_kernel<<<(E + 255) / 256, 256, 0, stream>>>(src, dst, cursor, src_sorted, E);
    wv_both_kernel<<<1, 256, 0, stream>>>(W_dst1, att_dst1, W_dst2, att_dst2, wv);

    int gemm_grid = (N + 63) / 64;
    int agg_grid = (N + 3) / 4;

    // ---- layer 1
    gemm_xw_fused<<<gemm_grid, 256, 0, stream>>>(x, W_src1, att_src1, wv, h_half,
                                                 a_src, a_dst, N);
    aggregate_kernel<<<agg_grid, 256, 0, stream>>>((const __half2*)h_half, a_src, a_dst,
                                                   row_start, src_sorted, bias1, feat, N, 1);
    // ---- layer 2
    gemm_xw_fused<<<gemm_grid, 256, 0, stream>>>(feat, W_src2, att_src2, wv + 128, h_half,
                                                 a_src, a_dst, N);
    aggregate_kernel<<<agg_grid, 256, 0, stream>>>((const __half2*)h_half, a_src, a_dst,
                                                   row_start, src_sorted, bias2, feat, N, 1);
    // ---- pool + linear
    int chunk = (N + 255) / 256;
    pool_kernel<<<256, 256, 0, stream>>>(feat, batch, sums, cnt, N, chunk);
    final_kernel<<<G, 128, 0, stream>>>(sums, cnt, W_lin, b_lin, out);
}

// Round 5
// 330.522 us; speedup vs baseline: 1.7796x; 1.1133x over previous
//
#include <hip/hip_runtime.h>
#include <hip/hip_bf16.h>
#include <hip/hip_fp16.h>

#define N_NODES 50000
#define N_EDGES 800000
#define N_GRAPHS 64

typedef _Float16 half_t;
typedef __attribute__((ext_vector_type(8))) _Float16 f16x8;
typedef __attribute__((ext_vector_type(4))) float f32x4;

// ---------------------------------------------------------------- CSR build
__global__ void build_deg_kernel(const int4* __restrict__ dst4, int* __restrict__ deg, int E4) {
    int tid = blockIdx.x * blockDim.x + threadIdx.x;
    if (tid < E4) {
        int4 d = dst4[tid];
        atomicAdd(&deg[d.x], 1);
        atomicAdd(&deg[d.y], 1);
        atomicAdd(&deg[d.z], 1);
        atomicAdd(&deg[d.w], 1);
    }
}

// ---- multi-block scan: 1024 elements per block
__global__ __launch_bounds__(256) void scan_partial(const int* __restrict__ deg,
                                                    int* __restrict__ block_sums, int n) {
    int b = blockIdx.x, t = threadIdx.x;
    int base = b * 1024 + t * 4;
    int4 v = make_int4(0, 0, 0, 0);
    if (base + 3 < n) v = *(const int4*)&deg[base];
    else {
        if (base + 0 < n) v.x = deg[base + 0];
        if (base + 1 < n) v.y = deg[base + 1];
        if (base + 2 < n) v.z = deg[base + 2];
    }
    int s = v.x + v.y + v.z + v.w;
    __shared__ int sm[256];
    sm[t] = s;
    __syncthreads();
    for (int off = 128; off; off >>= 1) {
        if (t < off) sm[t] += sm[t + off];
        __syncthreads();
    }
    if (t == 0) block_sums[b] = sm[0];
}

__global__ void scan_offsets(const int* __restrict__ block_sums, int* __restrict__ block_off,
                             int nb, int* __restrict__ total_out) {
    int lane = threadIdx.x;  // 64 threads
    int bs = (lane < nb) ? block_sums[lane] : 0;
    int v = bs;
    #pragma unroll
    for (int off = 1; off < 64; off <<= 1) {
        int u = __shfl_up(v, off, 64);
        if (lane >= off) v += u;
    }
    if (lane < nb) block_off[lane] = v - bs;   // exclusive
    if (lane == 63) *total_out = v;            // grand total -> row_start[n]
}

__global__ __launch_bounds__(256) void scan_final(const int* __restrict__ deg,
                                                  const int* __restrict__ block_off,
                                                  int* __restrict__ row_start,
                                                  int* __restrict__ cursor, int n) {
    int b = blockIdx.x, t = threadIdx.x;
    int base = b * 1024 + t * 4;
    int4 v = make_int4(0, 0, 0, 0);
    if (base + 3 < n) v = *(const int4*)&deg[base];
    else {
        if (base + 0 < n) v.x = deg[base + 0];
        if (base + 1 < n) v.y = deg[base + 1];
        if (base + 2 < n) v.z = deg[base + 2];
    }
    int s = v.x + v.y + v.z + v.w;
    __shared__ int sm[256];
    sm[t] = s;
    __syncthreads();
    for (int off = 1; off < 256; off <<= 1) {
        int u = (t >= off) ? sm[t - off] : 0;
        __syncthreads();
        sm[t] += u;
        __syncthreads();
    }
    int ex = block_off[b] + ((t == 0) ? 0 : sm[t - 1]);
    int r0 = ex, r1 = r0 + v.x, r2 = r1 + v.y, r3 = r2 + v.z;
    if (base + 0 < n) { row_start[base + 0] = r0; cursor[base + 0] = r0; }
    if (base + 1 < n) { row_start[base + 1] = r1; cursor[base + 1] = r1; }
    if (base + 2 < n) { row_start[base + 2] = r2; cursor[base + 2] = r2; }
    if (base + 3 < n) { row_start[base + 3] = r3; cursor[base + 3] = r3; }
}

__global__ void scatter_kernel(const int4* __restrict__ src4, const int4* __restrict__ dst4,
                               int* __restrict__ cursor, int* __restrict__ src_sorted, int E4) {
    int tid = blockIdx.x * blockDim.x + threadIdx.x;
    if (tid < E4) {
        int4 s = src4[tid];
        int4 d = dst4[tid];
        src_sorted[atomicAdd(&cursor[d.x], 1)] = s.x;
        src_sorted[atomicAdd(&cursor[d.y], 1)] = s.y;
        src_sorted[atomicAdd(&cursor[d.z], 1)] = s.z;
        src_sorted[atomicAdd(&cursor[d.w], 1)] = s.w;
    }
}

// both layers' wv in one launch: wv[i] = sum_j W[i,j]*att[j]
__global__ void wv_both_kernel(const float* __restrict__ W1, const float* __restrict__ a1,
                               const float* __restrict__ W2, const float* __restrict__ a2,
                               float* __restrict__ wv) {
    int t = threadIdx.x;                 // 256
    const float* W = (t < 128) ? W1 : W2;
    const float* a = (t < 128) ? a1 : a2;
    int i = t & 127;
    float s = 0.f;
    for (int j = 0; j < 128; j++) s += W[(size_t)i * 128 + j] * a[j];
    wv[t] = s;   // wv[0:128] = layer1, wv[128:256] = layer2
}

// ---------------------------------------------------------------- MFMA GEMM
// Hh[M,128](fp16) = X[M,128] @ W[128,128]
// fused: a_src_out[r] = (X@W)[r,:].att ;  a_dst_out[r] = X[r,:].wv
// Per-wave 16-row tile; mfma(A=W^T frag, B=X frag) -> D[n][m]: lane owns node
// row m0+(lane&15), feats n=(nt*16 + (lane>>4)*4 + i).  [layout per m89]
__global__ __launch_bounds__(256) void gemm_mfma_fused(const float* __restrict__ X,
                                                       const float* __restrict__ W,
                                                       const float* __restrict__ att,
                                                       const float* __restrict__ wv,
                                                       __half* __restrict__ Hh,
                                                       float* __restrict__ a_src_out,
                                                       float* __restrict__ a_dst_out, int M) {
    __shared__ half_t Wt[128][136];   // Wt[n][k] = W[k][n]; +8 halves pad
    int t = threadIdx.x;
    // stage W transposed as fp16 (coalesced float4 reads)
    #pragma unroll
    for (int i = 0; i < 16; i++) {
        int f4 = t + i * 256;            // < 4096
        int k = f4 >> 5;
        int n = (f4 & 31) * 4;
        float4 v = *(const float4*)&W[(size_t)f4 * 4];
        Wt[n + 0][k] = (half_t)v.x;
        Wt[n + 1][k] = (half_t)v.y;
        Wt[n + 2][k] = (half_t)v.z;
        Wt[n + 3][k] = (half_t)v.w;
    }
    __syncthreads();

    int lane = t & 63;
    int cl = lane & 15;     // node row within tile / W col within n-tile
    int g4 = lane >> 4;     // 0..3 k/row-group
    int gwave = blockIdx.x * 4 + (t >> 6);
    int nwaves = gridDim.x * 4;
    int ntiles = M >> 4;

    // preload att/wv slices this lane needs (L1-broadcast)
    float att_l[8][4];
    #pragma unroll
    for (int nt = 0; nt < 8; nt++)
        #pragma unroll
        for (int i = 0; i < 4; i++) att_l[nt][i] = att[nt * 16 + g4 * 4 + i];
    float wv_l[4][8];
    #pragma unroll
    for (int ks = 0; ks < 4; ks++)
        #pragma unroll
        for (int j = 0; j < 8; j++) wv_l[ks][j] = wv[ks * 32 + g4 * 8 + j];

    for (int tile = gwave; tile < ntiles; tile += nwaves) {
        int m0 = tile * 16;
        const float* xrow = X + (size_t)(m0 + cl) * 128;
        f32x4 acc[8];
        #pragma unroll
        for (int nt = 0; nt < 8; nt++) acc[nt] = (f32x4){0.f, 0.f, 0.f, 0.f};
        float adp = 0.f;

        #pragma unroll
        for (int ks = 0; ks < 4; ks++) {
            // B frag: X[m0+cl][ks*32 + g4*8 + j], j=0..7
            float4 v0 = *(const float4*)&xrow[ks * 32 + g4 * 8];
            float4 v1 = *(const float4*)&xrow[ks * 32 + g4 * 8 + 4];
            float xv[8] = {v0.x, v0.y, v0.z, v0.w, v1.x, v1.y, v1.z, v1.w};
            f16x8 bfrag;
            #pragma unroll
            for (int j = 0; j < 8; j++) {
                bfrag[j] = (half_t)xv[j];
                adp += xv[j] * wv_l[ks][j];
            }
            #pragma unroll
            for (int nt = 0; nt < 8; nt++) {
                f16x8 afrag = *(const f16x8*)&Wt[nt * 16 + cl][ks * 32 + g4 * 8];
                acc[nt] = __builtin_amdgcn_mfma_f32_16x16x32_f16(afrag, bfrag, acc[nt], 0, 0, 0);
            }
        }

        // fused a_src = H-row . att   (lane holds feats nt*16+g4*4+i of row m0+cl)
        float pr = 0.f;
        #pragma unroll
        for (int nt = 0; nt < 8; nt++)
            #pragma unroll
            for (int i = 0; i < 4; i++) pr += acc[nt][i] * att_l[nt][i];
        pr  += __shfl_xor(pr, 16, 64);  pr  += __shfl_xor(pr, 32, 64);
        float ad = adp;
        ad  += __shfl_xor(ad, 16, 64);  ad  += __shfl_xor(ad, 32, 64);
        if (lane < 16) { a_src_out[m0 + lane] = pr; a_dst_out[m0 + lane] = ad; }

        // H store: 8B per n-tile (4 consecutive halves)
        __half* hdst = Hh + (size_t)(m0 + cl) * 128 + g4 * 4;
        #pragma unroll
        for (int nt = 0; nt < 8; nt++) {
            __half h4[4];
            #pragma unroll
            for (int i = 0; i < 4; i++) h4[i] = __float2half(acc[nt][i]);
            *(uint2*)&hdst[nt * 16] = *(const uint2*)h4;
        }
    }
}

// ---------------------------------------------------------------- aggregation: wave per dst node, single pass, 8x ILP
__global__ __launch_bounds__(256) void aggregate_kernel(
    const __half2* __restrict__ h2, const float* __restrict__ a_src,
    const float* __restrict__ a_dst, const int* __restrict__ row_start,
    const int* __restrict__ src_sorted, const float* __restrict__ bias,
    float* __restrict__ out, int n, int do_relu) {
    int v = blockIdx.x * 4 + (threadIdx.x >> 6);
    if (v >= n) return;
    int lane = threadIdx.x & 63;
    int start = row_start[v];
    int end = row_start[v + 1];
    float adv = a_dst[v];
    const __half2* hbase = h2 + lane;

    float denom = 0.f, acc0 = 0.f, acc1 = 0.f;
    for (int c0 = start; c0 < end; c0 += 64) {
        int e = c0 + lane;
        int s = 0;
        float p = 0.f;
        if (e < end) {
            int si = src_sorted[e];
            s = si;
            float sc = a_src[si] + adv;
            sc = sc >= 0.f ? sc : 0.2f * sc;
            p = __expf(sc);   // scores are O(10): no max-subtraction needed in fp32
        }
        int cnt = min(64, end - c0);
        int j = 0;
        for (; j + 8 <= cnt; j += 8) {
            int   s0 = __shfl(s, j + 0, 64), s1 = __shfl(s, j + 1, 64),
                  s2 = __shfl(s, j + 2, 64), s3 = __shfl(s, j + 3, 64),
                  s4 = __shfl(s, j + 4, 64), s5 = __shfl(s, j + 5, 64),
                  s6 = __shfl(s, j + 6, 64), s7 = __shfl(s, j + 7, 64);
            float p0 = __shfl(p, j + 0, 64), p1 = __shfl(p, j + 1, 64),
                  p2 = __shfl(p, j + 2, 64), p3 = __shfl(p, j + 3, 64),
                  p4 = __shfl(p, j + 4, 64), p5 = __shfl(p, j + 5, 64),
                  p6 = __shfl(p, j + 6, 64), p7 = __shfl(p, j + 7, 64);
            __half2 r0 = hbase[(size_t)s0 * 64], r1 = hbase[(size_t)s1 * 64],
                    r2 = hbase[(size_t)s2 * 64], r3 = hbase[(size_t)s3 * 64],
                    r4 = hbase[(size_t)s4 * 64], r5 = hbase[(size_t)s5 * 64],
                    r6 = hbase[(size_t)s6 * 64], r7 = hbase[(size_t)s7 * 64];
            denom += (p0 + p1 + p2 + p3) + (p4 + p5 + p6 + p7);
            float2 f;
            f = __half22float2(r0); acc0 += p0 * f.x; acc1 += p0 * f.y;
            f = __half22float2(r1); acc0 += p1 * f.x; acc1 += p1 * f.y;
            f = __half22float2(r2); acc0 += p2 * f.x; acc1 += p2 * f.y;
            f = __half22float2(r3); acc0 += p3 * f.x; acc1 += p3 * f.y;
            f = __half22float2(r4); acc0 += p4 * f.x; acc1 += p4 * f.y;
            f = __half22float2(r5); acc0 += p5 * f.x; acc1 += p5 * f.y;
            f = __half22float2(r6); acc0 += p6 * f.x; acc1 += p6 * f.y;
            f = __half22float2(r7); acc0 += p7 * f.x; acc1 += p7 * f.y;
        }
        for (; j < cnt; j++) {
            int sj = __shfl(s, j, 64);
            float pj = __shfl(p, j, 64);
            float2 f = __half22float2(hbase[(size_t)sj * 64]);
            denom += pj;
            acc0 += pj * f.x;
            acc1 += pj * f.y;
        }
    }
    float inv = 1.f / (denom + 1e-16f);
    float o0 = acc0 * inv + bias[2 * lane];
    float o1 = acc1 * inv + bias[2 * lane + 1];
    if (do_relu) { o0 = fmaxf(o0, 0.f); o1 = fmaxf(o1, 0.f); }
    *(float2*)&out[(size_t)v * 128 + 2 * lane] = make_float2(o0, o1);
}

// ---------------------------------------------------------------- pooling (batch is sorted)
__global__ __launch_bounds__(256) void pool_kernel(const float* __restrict__ feat,
                                                   const int* __restrict__ batch,
                                                   float* __restrict__ sums, int* __restrict__ cnt,
                                                   int n, int chunk) {
    int start = blockIdx.x * chunk;
    int end = min(start + chunk, n);
    int t = threadIdx.x;
    int f = t & 127;
    int po = t >> 7;
    float acc = 0.f;
    int c = 0;
    int cur = -1;
    for (int nn = start + po; nn < end; nn += 2) {
        int g = batch[nn];
        if (g != cur) {
            if (cur >= 0) {
                atomicAdd(&sums[cur * 128 + f], acc);
                if (f == 0) atomicAdd(&cnt[cur], c);
            }
            acc = 0.f; c = 0; cur = g;
        }
        acc += feat[(size_t)nn * 128 + f];
        c++;
    }
    if (cur >= 0) {
        atomicAdd(&sums[cur * 128 + f], acc);
        if (f == 0) atomicAdd(&cnt[cur], c);
    }
}

__global__ void final_kernel(const float* __restrict__ sums, const int* __restrict__ cnt,
                             const float* __restrict__ Wl, const float* __restrict__ bl,
                             float* __restrict__ out) {
    int g = blockIdx.x, o = threadIdx.x;
    float invc = 1.f / fmaxf((float)cnt[g], 1.f);
    float acc = bl[o];
    for (int k = 0; k < 128; k++)
        acc += sums[g * 128 + k] * invc * Wl[k * 128 + o];
    out[g * 128 + o] = acc;
}

// ----------------------------------------------------------------
extern "C" void kernel_launch(void* const* d_in, const int* in_sizes, int n_in,
                              void* d_out, int out_size, void* d_ws, size_t ws_size,
                              hipStream_t stream) {
    const float* x        = (const float*)d_in[0];
    const int*   ei       = (const int*)d_in[1];
    const int*   batch    = (const int*)d_in[2];
    const float* W_src1   = (const float*)d_in[3];
    const float* W_dst1   = (const float*)d_in[4];
    const float* att_src1 = (const float*)d_in[5];
    const float* att_dst1 = (const float*)d_in[6];
    const float* bias1    = (const float*)d_in[7];
    const float* W_src2   = (const float*)d_in[8];
    const float* W_dst2   = (const float*)d_in[9];
    const float* att_src2 = (const float*)d_in[10];
    const float* att_dst2 = (const float*)d_in[11];
    const float* bias2    = (const float*)d_in[12];
    const float* W_lin    = (const float*)d_in[13];
    const float* b_lin    = (const float*)d_in[14];
    float* out = (float*)d_out;

    const int N = N_NODES, E = N_EDGES, G = N_GRAPHS;
    const int NB = (N + 1023) / 1024;
    const int E4 = E / 4;
    const int* src = ei;
    const int* dst = ei + E;

    char* w = (char*)d_ws;
    auto alloc = [&](size_t bytes) -> char* {
        char* p = w;
        w += (bytes + 255) & ~(size_t)255;
        return p;
    };
    // deg/sums/cnt contiguous -> single memset
    int*   deg        = (int*)alloc((size_t)N * 4);
    float* sums       = (float*)alloc((size_t)G * 128 * 4);
    int*   cnt        = (int*)alloc((size_t)G * 4);
    size_t zero_bytes = (((size_t)N * 4 + 255) & ~(size_t)255) + (((size_t)G * 128 * 4 + 255) & ~(size_t)255) + 256;

    int*   row_start  = (int*)alloc((size_t)(N + 1) * 4);
    int*   cursor     = (int*)alloc((size_t)N * 4);
    int*   block_sums = (int*)alloc(64 * 4);
    int*   block_off  = (int*)alloc(64 * 4);
    int*   src_sorted = (int*)alloc((size_t)E * 4);
    __half* h_half    = (__half*)alloc((size_t)N * 128 * 2);
    float* feat       = (float*)alloc((size_t)N * 128 * 4);
    float* a_src      = (float*)alloc((size_t)N * 4);
    float* a_dst      = (float*)alloc((size_t)N * 4);
    float* wv         = (float*)alloc(256 * 4);

    hipMemsetAsync(deg, 0, zero_bytes, stream);

    build_deg_kernel<<<(E4 + 255) / 256, 256, 0, stream>>>((const int4*)dst, deg, E4);
    scan_partial<<<NB, 256, 0, stream>>>(deg, block_sums, N);
    scan_offsets<<<1, 64, 0, stream>>>(block_sums, block_off, NB, &row_start[N]);
    scan_final<<<NB, 256, 0, stream>>>(deg, block_off, row_start, cursor, N);
    scatter_kernel<<<(E4 + 255) / 256, 256, 0, stream>>>((const int4*)src, (const int4*)dst,
                                                         cursor, src_sorted, E4);
    wv_both_kernel<<<1, 256, 0, stream>>>(W_dst1, att_dst1, W_dst2, att_dst2, wv);

    int agg_grid = (N + 3) / 4;

    // ---- layer 1
    gemm_mfma_fused<<<250, 256, 0, stream>>>(x, W_src1, att_src1, wv, h_half,
                                             a_src, a_dst, N);
    aggregate_kernel<<<agg_grid, 256, 0, stream>>>((const __half2*)h_half, a_src, a_dst,
                                                   row_start, src_sorted, bias1, feat, N, 1);
    // ---- layer 2
    gemm_mfma_fused<<<250, 256, 0, stream>>>(feat, W_src2, att_src2, wv + 128, h_half,
                                             a_src, a_dst, N);
    aggregate_kernel<<<agg_grid, 256, 0, stream>>>((const __half2*)h_half, a_src, a_dst,
                                                   row_start, src_sorted, bias2, feat, N, 1);
    // ---- pool + linear
    int chunk = (N + 255) / 256;
    pool_kernel<<<256, 256, 0, stream>>>(feat, batch, sums, cnt, N, chunk);
    final_kernel<<<G, 128, 0, stream>>>(sums, cnt, W_lin, b_lin, out);
}

// Round 6
// 286.638 us; speedup vs baseline: 2.0520x; 1.1531x over previous
//
#include <hip/hip_runtime.h>
#include <hip/hip_bf16.h>
#include <hip/hip_fp16.h>

#define N_NODES 50000
#define N_EDGES 800000
#define N_GRAPHS 64
#define NBUCK 196          // ceil(50000/256) coarse buckets (dst>>8)
#define NBLK 256           // edge-chunk blocks
#define EPB 3125           // edges per block (256*3125 = 800000)
#define MAXB 4864          // LDS pair-stage capacity (mean 4096, +12 sigma)

typedef _Float16 half_t;
typedef __attribute__((ext_vector_type(8))) _Float16 f16x8;
typedef __attribute__((ext_vector_type(4))) float f32x4;

// ---------------------------------------------------------------- bucketed CSR build
// k1: per-block histogram of coarse buckets
__global__ __launch_bounds__(256) void bucket_count_kernel(const int* __restrict__ dst,
                                                           int* __restrict__ counts, int E) {
    int b = blockIdx.x, t = threadIdx.x;
    __shared__ int lc[256];
    lc[t] = 0;
    __syncthreads();
    int s0 = b * EPB, s1 = min(s0 + EPB, E);
    for (int i = s0 + t; i < s1; i += 256) atomicAdd(&lc[dst[i] >> 8], 1);
    __syncthreads();
    if (t < NBUCK) counts[t * NBLK + b] = lc[t];
}

// k2: bucket bases + per-(bucket,block) exclusive offsets
__global__ __launch_bounds__(256) void bucket_scan_kernel(const int* __restrict__ counts,
                                                          int* __restrict__ off,
                                                          int* __restrict__ bucket_base) {
    int t = threadIdx.x;  // 256
    int total = 0;
    if (t < NBUCK) {
        const int* row = counts + t * NBLK;
        for (int b = 0; b < NBLK; b++) total += row[b];
    }
    __shared__ int sm[256];
    sm[t] = total;
    __syncthreads();
    for (int o = 1; o < 256; o <<= 1) {
        int u = (t >= o) ? sm[t - o] : 0;
        __syncthreads();
        sm[t] += u;
        __syncthreads();
    }
    int base = sm[t] - total;  // exclusive
    if (t < NBUCK) {
        bucket_base[t] = base;
        int run = base;
        const int* row = counts + t * NBLK;
        int* orow = off + t * NBLK;
        for (int b = 0; b < NBLK; b++) { orow[b] = run; run += row[b]; }
    }
    if (t == NBUCK - 1) bucket_base[NBUCK] = sm[t];
}

// k3: scatter (src,dst) pairs into per-(block,bucket) contiguous runs
__global__ __launch_bounds__(256) void pair_scatter_kernel(const int* __restrict__ src,
                                                           const int* __restrict__ dst,
                                                           const int* __restrict__ off,
                                                           int2* __restrict__ pairs, int E) {
    int b = blockIdx.x, t = threadIdx.x;
    __shared__ int lcur[256];
    if (t < NBUCK) lcur[t] = off[t * NBLK + b];
    __syncthreads();
    int s0 = b * EPB, s1 = min(s0 + EPB, E);
    for (int i = s0 + t; i < s1; i += 256) {
        int s = src[i], d = dst[i];
        int pos = atomicAdd(&lcur[d >> 8], 1);
        pairs[pos] = make_int2(s, d);
    }
}

// k4: per-bucket fine CSR — row_start + src_sorted, single-writer contiguous region
__global__ __launch_bounds__(256) void fine_csr_kernel(const int2* __restrict__ pairs,
                                                       const int* __restrict__ bucket_base,
                                                       int* __restrict__ row_start,
                                                       int* __restrict__ src_sorted,
                                                       int n, int E) {
    int b = blockIdx.x, t = threadIdx.x;
    int base = bucket_base[b];
    int cntb = bucket_base[b + 1] - base;
    __shared__ int lc[256], lcur[256], sm[256];
    __shared__ int2 sp[MAXB];
    lc[t] = 0;
    __syncthreads();
    bool staged = (cntb <= MAXB);
    for (int i = t; i < cntb; i += 256) {
        int2 p = pairs[base + i];
        if (staged) sp[i] = p;
        atomicAdd(&lc[p.y & 255], 1);
    }
    __syncthreads();
    sm[t] = lc[t];
    __syncthreads();
    for (int o = 1; o < 256; o <<= 1) {
        int u = (t >= o) ? sm[t - o] : 0;
        __syncthreads();
        sm[t] += u;
        __syncthreads();
    }
    int excl = sm[t] - lc[t];
    int node = (b << 8) + t;
    if (node < n) row_start[node] = base + excl;
    if (b == 0 && t == 0) row_start[n] = E;
    lcur[t] = excl;
    __syncthreads();
    for (int i = t; i < cntb; i += 256) {
        int2 p = staged ? sp[i] : pairs[base + i];
        int pos = atomicAdd(&lcur[p.y & 255], 1);
        src_sorted[base + pos] = p.x;
    }
}

// both layers' wv in one launch: wv[i] = sum_j W[i,j]*att[j]
__global__ void wv_both_kernel(const float* __restrict__ W1, const float* __restrict__ a1,
                               const float* __restrict__ W2, const float* __restrict__ a2,
                               float* __restrict__ wv) {
    int t = threadIdx.x;                 // 256
    const float* W = (t < 128) ? W1 : W2;
    const float* a = (t < 128) ? a1 : a2;
    int i = t & 127;
    float s = 0.f;
    for (int j = 0; j < 128; j++) s += W[(size_t)i * 128 + j] * a[j];
    wv[t] = s;   // wv[0:128] = layer1, wv[128:256] = layer2
}

// ---------------------------------------------------------------- MFMA GEMM
// Hh[M,128](fp16) = X[M,128] @ W[128,128]
// fused: a_src_out[r] = (X@W)[r,:].att ;  a_dst_out[r] = X[r,:].wv
__global__ __launch_bounds__(256) void gemm_mfma_fused(const float* __restrict__ X,
                                                       const float* __restrict__ W,
                                                       const float* __restrict__ att,
                                                       const float* __restrict__ wv,
                                                       __half* __restrict__ Hh,
                                                       float* __restrict__ a_src_out,
                                                       float* __restrict__ a_dst_out, int M) {
    __shared__ half_t Wt[128][136];   // Wt[n][k] = W[k][n]; +8 halves pad
    int t = threadIdx.x;
    #pragma unroll
    for (int i = 0; i < 16; i++) {
        int f4 = t + i * 256;            // < 4096
        int k = f4 >> 5;
        int n = (f4 & 31) * 4;
        float4 v = *(const float4*)&W[(size_t)f4 * 4];
        Wt[n + 0][k] = (half_t)v.x;
        Wt[n + 1][k] = (half_t)v.y;
        Wt[n + 2][k] = (half_t)v.z;
        Wt[n + 3][k] = (half_t)v.w;
    }
    __syncthreads();

    int lane = t & 63;
    int cl = lane & 15;
    int g4 = lane >> 4;
    int gwave = blockIdx.x * 4 + (t >> 6);
    int nwaves = gridDim.x * 4;
    int ntiles = M >> 4;

    float att_l[8][4];
    #pragma unroll
    for (int nt = 0; nt < 8; nt++)
        #pragma unroll
        for (int i = 0; i < 4; i++) att_l[nt][i] = att[nt * 16 + g4 * 4 + i];
    float wv_l[4][8];
    #pragma unroll
    for (int ks = 0; ks < 4; ks++)
        #pragma unroll
        for (int j = 0; j < 8; j++) wv_l[ks][j] = wv[ks * 32 + g4 * 8 + j];

    for (int tile = gwave; tile < ntiles; tile += nwaves) {
        int m0 = tile * 16;
        const float* xrow = X + (size_t)(m0 + cl) * 128;
        f32x4 acc[8];
        #pragma unroll
        for (int nt = 0; nt < 8; nt++) acc[nt] = (f32x4){0.f, 0.f, 0.f, 0.f};
        float adp = 0.f;

        #pragma unroll
        for (int ks = 0; ks < 4; ks++) {
            float4 v0 = *(const float4*)&xrow[ks * 32 + g4 * 8];
            float4 v1 = *(const float4*)&xrow[ks * 32 + g4 * 8 + 4];
            float xv[8] = {v0.x, v0.y, v0.z, v0.w, v1.x, v1.y, v1.z, v1.w};
            f16x8 bfrag;
            #pragma unroll
            for (int j = 0; j < 8; j++) {
                bfrag[j] = (half_t)xv[j];
                adp += xv[j] * wv_l[ks][j];
            }
            #pragma unroll
            for (int nt = 0; nt < 8; nt++) {
                f16x8 afrag = *(const f16x8*)&Wt[nt * 16 + cl][ks * 32 + g4 * 8];
                acc[nt] = __builtin_amdgcn_mfma_f32_16x16x32_f16(afrag, bfrag, acc[nt], 0, 0, 0);
            }
        }

        float pr = 0.f;
        #pragma unroll
        for (int nt = 0; nt < 8; nt++)
            #pragma unroll
            for (int i = 0; i < 4; i++) pr += acc[nt][i] * att_l[nt][i];
        pr += __shfl_xor(pr, 16, 64);  pr += __shfl_xor(pr, 32, 64);
        float ad = adp;
        ad += __shfl_xor(ad, 16, 64);  ad += __shfl_xor(ad, 32, 64);
        if (lane < 16) { a_src_out[m0 + lane] = pr; a_dst_out[m0 + lane] = ad; }

        __half* hdst = Hh + (size_t)(m0 + cl) * 128 + g4 * 4;
        #pragma unroll
        for (int nt = 0; nt < 8; nt++) {
            __half h4[4];
            #pragma unroll
            for (int i = 0; i < 4; i++) h4[i] = __float2half(acc[nt][i]);
            *(uint2*)&hdst[nt * 16] = *(const uint2*)h4;
        }
    }
}

// ---------------------------------------------------------------- aggregation: wave per dst node, single pass, 8x ILP
__global__ __launch_bounds__(256) void aggregate_kernel(
    const __half2* __restrict__ h2, const float* __restrict__ a_src,
    const float* __restrict__ a_dst, const int* __restrict__ row_start,
    const int* __restrict__ src_sorted, const float* __restrict__ bias,
    float* __restrict__ out, int n, int do_relu) {
    int v = blockIdx.x * 4 + (threadIdx.x >> 6);
    if (v >= n) return;
    int lane = threadIdx.x & 63;
    int start = row_start[v];
    int end = row_start[v + 1];
    float adv = a_dst[v];
    const __half2* hbase = h2 + lane;

    float denom = 0.f, acc0 = 0.f, acc1 = 0.f;
    for (int c0 = start; c0 < end; c0 += 64) {
        int e = c0 + lane;
        int s = 0;
        float p = 0.f;
        if (e < end) {
            int si = src_sorted[e];
            s = si;
            float sc = a_src[si] + adv;
            sc = sc >= 0.f ? sc : 0.2f * sc;
            p = __expf(sc);   // scores are O(10): no max-subtraction needed in fp32
        }
        int cnt = min(64, end - c0);
        int j = 0;
        for (; j + 8 <= cnt; j += 8) {
            int   s0 = __shfl(s, j + 0, 64), s1 = __shfl(s, j + 1, 64),
                  s2 = __shfl(s, j + 2, 64), s3 = __shfl(s, j + 3, 64),
                  s4 = __shfl(s, j + 4, 64), s5 = __shfl(s, j + 5, 64),
                  s6 = __shfl(s, j + 6, 64), s7 = __shfl(s, j + 7, 64);
            float p0 = __shfl(p, j + 0, 64), p1 = __shfl(p, j + 1, 64),
                  p2 = __shfl(p, j + 2, 64), p3 = __shfl(p, j + 3, 64),
                  p4 = __shfl(p, j + 4, 64), p5 = __shfl(p, j + 5, 64),
                  p6 = __shfl(p, j + 6, 64), p7 = __shfl(p, j + 7, 64);
            __half2 r0 = hbase[(size_t)s0 * 64], r1 = hbase[(size_t)s1 * 64],
                    r2 = hbase[(size_t)s2 * 64], r3 = hbase[(size_t)s3 * 64],
                    r4 = hbase[(size_t)s4 * 64], r5 = hbase[(size_t)s5 * 64],
                    r6 = hbase[(size_t)s6 * 64], r7 = hbase[(size_t)s7 * 64];
            denom += (p0 + p1 + p2 + p3) + (p4 + p5 + p6 + p7);
            float2 f;
            f = __half22float2(r0); acc0 += p0 * f.x; acc1 += p0 * f.y;
            f = __half22float2(r1); acc0 += p1 * f.x; acc1 += p1 * f.y;
            f = __half22float2(r2); acc0 += p2 * f.x; acc1 += p2 * f.y;
            f = __half22float2(r3); acc0 += p3 * f.x; acc1 += p3 * f.y;
            f = __half22float2(r4); acc0 += p4 * f.x; acc1 += p4 * f.y;
            f = __half22float2(r5); acc0 += p5 * f.x; acc1 += p5 * f.y;
            f = __half22float2(r6); acc0 += p6 * f.x; acc1 += p6 * f.y;
            f = __half22float2(r7); acc0 += p7 * f.x; acc1 += p7 * f.y;
        }
        for (; j < cnt; j++) {
            int sj = __shfl(s, j, 64);
            float pj = __shfl(p, j, 64);
            float2 f = __half22float2(hbase[(size_t)sj * 64]);
            denom += pj;
            acc0 += pj * f.x;
            acc1 += pj * f.y;
        }
    }
    float inv = 1.f / (denom + 1e-16f);
    float o0 = acc0 * inv + bias[2 * lane];
    float o1 = acc1 * inv + bias[2 * lane + 1];
    if (do_relu) { o0 = fmaxf(o0, 0.f); o1 = fmaxf(o1, 0.f); }
    *(float2*)&out[(size_t)v * 128 + 2 * lane] = make_float2(o0, o1);
}

// ---------------------------------------------------------------- pooling (batch is sorted)
__global__ __launch_bounds__(256) void pool_kernel(const float* __restrict__ feat,
                                                   const int* __restrict__ batch,
                                                   float* __restrict__ sums, int* __restrict__ cnt,
                                                   int n, int chunk) {
    int start = blockIdx.x * chunk;
    int end = min(start + chunk, n);
    int t = threadIdx.x;
    int f = t & 127;
    int po = t >> 7;
    float acc = 0.f;
    int c = 0;
    int cur = -1;
    for (int nn = start + po; nn < end; nn += 2) {
        int g = batch[nn];
        if (g != cur) {
            if (cur >= 0) {
                atomicAdd(&sums[cur * 128 + f], acc);
                if (f == 0) atomicAdd(&cnt[cur], c);
            }
            acc = 0.f; c = 0; cur = g;
        }
        acc += feat[(size_t)nn * 128 + f];
        c++;
    }
    if (cur >= 0) {
        atomicAdd(&sums[cur * 128 + f], acc);
        if (f == 0) atomicAdd(&cnt[cur], c);
    }
}

__global__ void final_kernel(const float* __restrict__ sums, const int* __restrict__ cnt,
                             const float* __restrict__ Wl, const float* __restrict__ bl,
                             float* __restrict__ out) {
    int g = blockIdx.x, o = threadIdx.x;
    float invc = 1.f / fmaxf((float)cnt[g], 1.f);
    float acc = bl[o];
    for (int k = 0; k < 128; k++)
        acc += sums[g * 128 + k] * invc * Wl[k * 128 + o];
    out[g * 128 + o] = acc;
}

// ----------------------------------------------------------------
extern "C" void kernel_launch(void* const* d_in, const int* in_sizes, int n_in,
                              void* d_out, int out_size, void* d_ws, size_t ws_size,
                              hipStream_t stream) {
    const float* x        = (const float*)d_in[0];
    const int*   ei       = (const int*)d_in[1];
    const int*   batch    = (const int*)d_in[2];
    const float* W_src1   = (const float*)d_in[3];
    const float* W_dst1   = (const float*)d_in[4];
    const float* att_src1 = (const float*)d_in[5];
    const float* att_dst1 = (const float*)d_in[6];
    const float* bias1    = (const float*)d_in[7];
    const float* W_src2   = (const float*)d_in[8];
    const float* W_dst2   = (const float*)d_in[9];
    const float* att_src2 = (const float*)d_in[10];
    const float* att_dst2 = (const float*)d_in[11];
    const float* bias2    = (const float*)d_in[12];
    const float* W_lin    = (const float*)d_in[13];
    const float* b_lin    = (const float*)d_in[14];
    float* out = (float*)d_out;

    const int N = N_NODES, E = N_EDGES, G = N_GRAPHS;
    const int* src = ei;
    const int* dst = ei + E;

    char* w = (char*)d_ws;
    auto alloc = [&](size_t bytes) -> char* {
        char* p = w;
        w += (bytes + 255) & ~(size_t)255;
        return p;
    };
    // sums/cnt first, contiguous -> single memset
    float* sums       = (float*)alloc((size_t)G * 128 * 4);
    int*   cnt        = (int*)alloc((size_t)G * 4);
    size_t zero_bytes = (((size_t)G * 128 * 4 + 255) & ~(size_t)255) + 256;

    int*   counts     = (int*)alloc((size_t)NBUCK * NBLK * 4);
    int*   off        = (int*)alloc((size_t)NBUCK * NBLK * 4);
    int*   bucket_base= (int*)alloc((size_t)(NBUCK + 1) * 4);
    int2*  pairs      = (int2*)alloc((size_t)E * 8);
    int*   row_start  = (int*)alloc((size_t)(N + 1) * 4);
    int*   src_sorted = (int*)alloc((size_t)E * 4);
    __half* h_half    = (__half*)alloc((size_t)N * 128 * 2);
    float* feat       = (float*)alloc((size_t)N * 128 * 4);
    float* a_src      = (float*)alloc((size_t)N * 4);
    float* a_dst      = (float*)alloc((size_t)N * 4);
    float* wv         = (float*)alloc(256 * 4);

    hipMemsetAsync(sums, 0, zero_bytes, stream);

    bucket_count_kernel<<<NBLK, 256, 0, stream>>>(dst, counts, E);
    bucket_scan_kernel<<<1, 256, 0, stream>>>(counts, off, bucket_base);
    pair_scatter_kernel<<<NBLK, 256, 0, stream>>>(src, dst, off, pairs, E);
    fine_csr_kernel<<<NBUCK, 256, 0, stream>>>(pairs, bucket_base, row_start, src_sorted, N, E);
    wv_both_kernel<<<1, 256, 0, stream>>>(W_dst1, att_dst1, W_dst2, att_dst2, wv);

    int agg_grid = (N + 3) / 4;

    // ---- layer 1
    gemm_mfma_fused<<<250, 256, 0, stream>>>(x, W_src1, att_src1, wv, h_half,
                                             a_src, a_dst, N);
    aggregate_kernel<<<agg_grid, 256, 0, stream>>>((const __half2*)h_half, a_src, a_dst,
                                                   row_start, src_sorted, bias1, feat, N, 1);
    // ---- layer 2
    gemm_mfma_fused<<<250, 256, 0, stream>>>(feat, W_src2, att_src2, wv + 128, h_half,
                                             a_src, a_dst, N);
    aggregate_kernel<<<agg_grid, 256, 0, stream>>>((const __half2*)h_half, a_src, a_dst,
                                                   row_start, src_sorted, bias2, feat, N, 1);
    // ---- pool + linear
    int chunk = (N + 255) / 256;
    pool_kernel<<<256, 256, 0, stream>>>(feat, batch, sums, cnt, N, chunk);
    final_kernel<<<G, 128, 0, stream>>>(sums, cnt, W_lin, b_lin, out);
}